// Round 18
// baseline (2871.498 us; speedup 1.0000x reference)
//
#include <hip/hip_runtime.h>

typedef _Float16 f16;
typedef __attribute__((ext_vector_type(8))) _Float16 f16x8;
typedef __attribute__((ext_vector_type(4))) _Float16 f16x4;
typedef __attribute__((ext_vector_type(4))) float f32x4;

#define T_STEPS 784
#define HDIM    512
#define COUT    10

#define XH_OFF   (512 * 1024)

#define MFMA16(a, b, c) __builtin_amdgcn_mfma_f32_16x16x32_f16((a), (b), (c), 0, 0, 0)
#define BAR_LGKM() asm volatile("s_waitcnt lgkmcnt(0)\n\ts_barrier" ::: "memory")

// W_rec f32 -> fp16, frag-major: frag f = (w*4+n)*16+kk:
//   Wf[f*512 + lane*8 + j] = W_rec[w*64+n*16+(lane&15)][kk*32+(lane>>4)*8+j]
__global__ void cvt_w(const float* __restrict__ W, f16* __restrict__ Wf) {
    const int c  = blockIdx.x * 256 + threadIdx.x;
    const int l  = c & 63;
    const int kk = (c >> 6) & 15;
    const int n  = (c >> 10) & 3;
    const int w  = c >> 12;
    const int row = w * 64 + n * 16 + (l & 15);
    const int col = kk * 32 + (l >> 4) * 8;
    const float* s = W + row * HDIM + col;
    f16* d = Wf + (size_t)c * 8;
#pragma unroll
    for (int j = 0; j < 8; ++j) d[j] = (f16)s[j];
}

// xh[t][b] = (f16) x[b][perm[t]]
__global__ void permute_x(const float* __restrict__ x, const int* __restrict__ perm,
                          f16* __restrict__ xh) {
    const int i = blockIdx.x * 256 + threadIdx.x;
    const int t = i >> 10, b = i & 1023;
    xh[i] = (f16)x[b * T_STEPS + perm[t]];
}

// ---- main: in-CU recurrence, NO cross-WG sync -------------------------------
// 64 WGs x 512 thr (8 waves, 2/SIMD, 256-reg budget). WG owns 16 batch rows;
// wave w owns outcols [w*64, w*64+64) (otiles n=0..3).
// W: kk 0..3 A-frags resident in 64 regs, pinned by a LOOP-CARRIED asm
// dependence (each iteration's wr is the previous iteration's asm output ->
// remat/sink is illegal). kk 4..15 streamed via 4-deep ring + per-WG rotation.
// h: double-buffered 2x16 KB LDS (frag-major), ONE lgkm barrier per step.
// LDS traffic/step = B-frags only (128 KB/CU) -- half of r16.
__global__ __launch_bounds__(512)
__attribute__((amdgpu_waves_per_eu(2, 2)))
void rnn_res(const float* __restrict__ W_in, const f16* __restrict__ Wf,
             const f16* __restrict__ xh, const float* __restrict__ W_out,
             const float* __restrict__ b_out, float* __restrict__ out)
{
    __shared__ __align__(16) char hb[32768];   // 2 x 16 frags x 1 KB
    const int tid  = threadIdx.x;
    const int w    = tid >> 6;
    const int lane = tid & 63;
    const int b_   = lane & 15;
    const int lhi  = lane >> 4;
    const int b0   = blockIdx.x * 16;

    for (int i = tid; i < 4096; i += 512) ((int*)hb)[i] = 0;  // h0 = 0 (buf0)

    const f16* wb = Wf + (size_t)w * 32768 + lane * 8;
#define LDW(kk, n) (*(const f16x8*)(wb + ((n) * 16 + (kk)) * 512))

    // resident W: kk 0..3 x 4 otiles (64 regs/lane)
    f16x8 wr[16];
#pragma unroll
    for (int kk = 0; kk < 4; ++kk)
#pragma unroll
        for (int n = 0; n < 4; ++n)
            wr[kk * 4 + n] = LDW(kk, n);

    f16x4 win[4];
#pragma unroll
    for (int n = 0; n < 4; ++n)
#pragma unroll
        for (int r = 0; r < 4; ++r)
            win[n][r] = (f16)W_in[w * 64 + n * 16 + lhi * 4 + r];

    // h LDS addresses (frag-major, r6-proven)
    char* const rb = hb + lane * 16;
    int wa[4];
#pragma unroll
    for (int n = 0; n < 4; ++n)
        wa[n] = (2 * w + (n >> 1)) * 1024
              + (((((n & 1) * 2 + (lhi >> 1)) << 4) | b_) * 16)
              + (lhi & 1) * 8;

    // per-WG rotation of streamed slice order (kk 4..15), r16-proven
    const int rot = (int)((blockIdx.x * 7u) % 12u);
    int ks[12];
#pragma unroll
    for (int i = 0; i < 12; ++i) {
        int v = i + rot; if (v >= 12) v -= 12;
        ks[i] = 4 + v;
    }

    __syncthreads();   // h zero ready

    // preload ring with first 4 streamed slices
    f16x8 r0[4], r1[4], r2[4], r3[4];
#pragma unroll
    for (int n = 0; n < 4; ++n) r0[n] = LDW(ks[0], n);
#pragma unroll
    for (int n = 0; n < 4; ++n) r1[n] = LDW(ks[1], n);
#pragma unroll
    for (int n = 0; n < 4; ++n) r2[n] = LDW(ks[2], n);
#pragma unroll
    for (int n = 0; n < 4; ++n) r3[n] = LDW(ks[3], n);

#define RES_KK(ck)                                                  \
    {                                                               \
        const f16x8 bh = *(const f16x8*)(rp + (ck) * 1024);         \
        acc0 = MFMA16(wr[(ck) * 4 + 0], bh, acc0);                  \
        acc1 = MFMA16(wr[(ck) * 4 + 1], bh, acc1);                  \
        acc2 = MFMA16(wr[(ck) * 4 + 2], bh, acc2);                  \
        acc3 = MFMA16(wr[(ck) * 4 + 3], bh, acc3);                  \
    }
#define STEP_KK(kki, RING, nxtk)                                    \
    {                                                               \
        const f16x8 bh = *(const f16x8*)(rp + (kki) * 1024);        \
        acc0 = MFMA16(RING[0], bh, acc0);                           \
        acc1 = MFMA16(RING[1], bh, acc1);                           \
        acc2 = MFMA16(RING[2], bh, acc2);                           \
        acc3 = MFMA16(RING[3], bh, acc3);                           \
        RING[0] = LDW(nxtk, 0); RING[1] = LDW(nxtk, 1);             \
        RING[2] = LDW(nxtk, 2); RING[3] = LDW(nxtk, 3);             \
    }

    int cur = 0;
#pragma unroll 1
    for (int t = 0; t < T_STEPS; ++t) {
        // loop-carried opacity: wr(t) = asm(wr(t-1)) -- cannot be remat'd/sunk
#pragma unroll
        for (int i = 0; i < 16; ++i)
            asm volatile("" : "+v"(wr[i]));

        const float xv = (float)xh[t * 1024 + b0 + b_];
        const char* rp = rb + cur;
        char* wq = hb + (cur ^ 16384);

        f32x4 acc0 = {0.f, 0.f, 0.f, 0.f};
        f32x4 acc1 = {0.f, 0.f, 0.f, 0.f};
        f32x4 acc2 = {0.f, 0.f, 0.f, 0.f};
        f32x4 acc3 = {0.f, 0.f, 0.f, 0.f};

        // resident slices first: pure reg/LDS compute while the ring flies
        RES_KK(0) RES_KK(1) RES_KK(2) RES_KK(3)
        // streamed slices (rotated order); tail reloads prefetch next step
        STEP_KK(ks[0], r0, ks[4])   STEP_KK(ks[1], r1, ks[5])
        STEP_KK(ks[2], r2, ks[6])   STEP_KK(ks[3], r3, ks[7])
        STEP_KK(ks[4], r0, ks[8])   STEP_KK(ks[5], r1, ks[9])
        STEP_KK(ks[6], r2, ks[10])  STEP_KK(ks[7], r3, ks[11])
        STEP_KK(ks[8], r0, ks[0])   STEP_KK(ks[9], r1, ks[1])
        STEP_KK(ks[10], r2, ks[2])  STEP_KK(ks[11], r3, ks[3])

        // epilogue: inject + relu, 4 x 8B stores into the other h buffer
        {
            f16x4 hv;
            float v;
#define EPI(n, ACC)                                                  \
            v = ACC[0] + xv * (float)win[n][0]; hv[0] = (f16)fmaxf(v, 0.f); \
            v = ACC[1] + xv * (float)win[n][1]; hv[1] = (f16)fmaxf(v, 0.f); \
            v = ACC[2] + xv * (float)win[n][2]; hv[2] = (f16)fmaxf(v, 0.f); \
            v = ACC[3] + xv * (float)win[n][3]; hv[3] = (f16)fmaxf(v, 0.f); \
            *(f16x4*)(wq + wa[n]) = hv;
            EPI(0, acc0) EPI(1, acc1) EPI(2, acc2) EPI(3, acc3)
#undef EPI
        }

        BAR_LGKM();   // single barrier: h(t+1) visible; ring stays in flight
        cur ^= 16384;
    }

    // projection: out[b,c] = h_last[b,:] . W_out[c,:] + b_out[c]
    if (tid < 16 * COUT) {
        const int bb = tid / COUT, c = tid % COUT;
        const char* hr = hb + cur;
        float s_ = b_out[c];
        const float* wo = W_out + c * HDIM;
#pragma unroll 4
        for (int o0 = 0; o0 < HDIM; o0 += 8) {
            const int off = (o0 >> 5) * 1024 + (((((o0 >> 3) & 3) << 4) | bb) * 16);
            f16x8 hv = *(const f16x8*)(hr + off);
#pragma unroll
            for (int jj = 0; jj < 8; ++jj)
                s_ += (float)hv[jj] * wo[o0 + jj];
        }
        out[(b0 + bb) * COUT + c] = s_;
    }
}

extern "C" void kernel_launch(void* const* d_in, const int* in_sizes, int n_in,
                              void* d_out, int out_size, void* d_ws, size_t ws_size,
                              hipStream_t stream)
{
    (void)in_sizes; (void)n_in; (void)out_size; (void)ws_size;
    const float* x     = (const float*)d_in[0];
    const float* W_in  = (const float*)d_in[1];
    const float* W_rec = (const float*)d_in[2];
    const float* W_out = (const float*)d_in[3];
    const float* b_out = (const float*)d_in[4];
    const int*   perm  = (const int*)d_in[5];
    float* out = (float*)d_out;

    f16* Wf  = (f16*)d_ws;                           // 512 KB
    f16* xhp = (f16*)((char*)d_ws + XH_OFF);         // 1.6 MB

    cvt_w<<<dim3(128), dim3(256), 0, stream>>>(W_rec, Wf);
    permute_x<<<dim3(T_STEPS * 1024 / 256), dim3(256), 0, stream>>>(x, perm, xhp);
    rnn_res<<<dim3(64), dim3(512), 0, stream>>>(W_in, Wf, xhp, W_out, b_out, out);
}

// Round 19
// 1160.495 us; speedup vs baseline: 2.4744x; 2.4744x over previous
//
#include <hip/hip_runtime.h>

typedef _Float16 f16;
typedef __attribute__((ext_vector_type(8))) _Float16 f16x8;
typedef __attribute__((ext_vector_type(4))) _Float16 f16x4;
typedef __attribute__((ext_vector_type(4))) float f32x4;

#define T_STEPS 784
#define HDIM    512
#define COUT    10

#define XH_OFF   (512 * 1024)

#define MFMA16(a, b, c) __builtin_amdgcn_mfma_f32_16x16x32_f16((a), (b), (c), 0, 0, 0)
#define BAR_LGKM() asm volatile("s_waitcnt lgkmcnt(0)\n\ts_barrier" ::: "memory")

// W_rec f32 -> fp16, frag-major: frag f = (w*4+n)*16+kk:
//   Wf[f*512 + lane*8 + j] = W_rec[w*64+n*16+(lane&15)][kk*32+(lane>>4)*8+j]
__global__ void cvt_w(const float* __restrict__ W, f16* __restrict__ Wf) {
    const int c  = blockIdx.x * 256 + threadIdx.x;
    const int l  = c & 63;
    const int kk = (c >> 6) & 15;
    const int n  = (c >> 10) & 3;
    const int w  = c >> 12;
    const int row = w * 64 + n * 16 + (l & 15);
    const int col = kk * 32 + (l >> 4) * 8;
    const float* s = W + row * HDIM + col;
    f16* d = Wf + (size_t)c * 8;
#pragma unroll
    for (int j = 0; j < 8; ++j) d[j] = (f16)s[j];
}

// xh[t][b] = (f16) x[b][perm[t]]
__global__ void permute_x(const float* __restrict__ x, const int* __restrict__ perm,
                          f16* __restrict__ xh) {
    const int i = blockIdx.x * 256 + threadIdx.x;
    const int t = i >> 10, b = i & 1023;
    xh[i] = (f16)x[b * T_STEPS + perm[t]];
}

// ---- main: in-CU recurrence, NO cross-WG sync -------------------------------
// 64 WGs x 512 thr (8 waves, 2/SIMD). WG owns 16 batch rows, all 512 outcols;
// wave w owns outcols [w*64, w*64+64) (otiles n=0..3).
// W: kk 0..3 A-frags cached in LDS (128 KB, filled once); kk 4..15 streamed
// from L2 per step via 4-deep register ring with per-WG rotation (r16).
// h: DOUBLE-BUFFERED 2x16 KB LDS (r6-proven) -> ONE lgkm barrier per step.
// LDS total = 163840 B (full 160 KiB pool) -- also forces 1 WG/CU, which
// r17/r18 showed is load-bearing (2-WG packing halves per-CU L2 rate).
__global__ __launch_bounds__(512, 2)
void rnn_l2(const float* __restrict__ W_in, const f16* __restrict__ Wf,
            const f16* __restrict__ xh, const float* __restrict__ W_out,
            const float* __restrict__ b_out, float* __restrict__ out)
{
    __shared__ __align__(16) char lds[163840];   // [0,128K): W cache; [128K,160K): h dbuf
    char* const HB = lds + 131072;

    const int tid  = threadIdx.x;
    const int w    = tid >> 6;
    const int lane = tid & 63;
    const int b_   = lane & 15;
    const int lhi  = lane >> 4;
    const int b0   = blockIdx.x * 16;

    const f16* wb = Wf + (size_t)w * 32768 + lane * 8;
#define LDW(kk, n) (*(const f16x8*)(wb + ((n) * 16 + (kk)) * 512))

    // fill W cache: kk 0..3 for this wave's 4 otiles
#pragma unroll
    for (int n = 0; n < 4; ++n)
#pragma unroll
        for (int ck = 0; ck < 4; ++ck)
            *(f16x8*)(lds + (((w * 4 + n) * 4 + ck) * 1024) + lane * 16) = LDW(ck, n);

    // zero h buffer 0 (h0 = 0)
    for (int i = tid; i < 4096; i += 512) ((int*)HB)[i] = 0;

    f16x4 win[4];
#pragma unroll
    for (int n = 0; n < 4; ++n)
#pragma unroll
        for (int r = 0; r < 4; ++r)
            win[n][r] = (f16)W_in[w * 64 + n * 16 + lhi * 4 + r];

    // h LDS addresses (frag-major, r6-proven)
    char* const rb = HB + lane * 16;
    int wa[4];
#pragma unroll
    for (int n = 0; n < 4; ++n)
        wa[n] = (2 * w + (n >> 1)) * 1024
              + (((((n & 1) * 2 + (lhi >> 1)) << 4) | b_) * 16)
              + (lhi & 1) * 8;

    // per-WG rotation of streamed slice order (kk 4..15), r16-proven
    const int rot = (int)((blockIdx.x * 7u) % 12u);
    int ks[12];
#pragma unroll
    for (int i = 0; i < 12; ++i) {
        int v = i + rot; if (v >= 12) v -= 12;
        ks[i] = 4 + v;
    }

    __syncthreads();   // W cache + h zero ready

    // preload ring with first 4 streamed slices
    f16x8 r0[4], r1[4], r2[4], r3[4];
#pragma unroll
    for (int n = 0; n < 4; ++n) r0[n] = LDW(ks[0], n);
#pragma unroll
    for (int n = 0; n < 4; ++n) r1[n] = LDW(ks[1], n);
#pragma unroll
    for (int n = 0; n < 4; ++n) r2[n] = LDW(ks[2], n);
#pragma unroll
    for (int n = 0; n < 4; ++n) r3[n] = LDW(ks[3], n);

#define STEP_KK(kki, RING, nxtk)                                    \
    {                                                               \
        const f16x8 bh = *(const f16x8*)(rp + (kki) * 1024);        \
        acc0 = MFMA16(RING[0], bh, acc0);                           \
        acc1 = MFMA16(RING[1], bh, acc1);                           \
        acc2 = MFMA16(RING[2], bh, acc2);                           \
        acc3 = MFMA16(RING[3], bh, acc3);                           \
        RING[0] = LDW(nxtk, 0); RING[1] = LDW(nxtk, 1);             \
        RING[2] = LDW(nxtk, 2); RING[3] = LDW(nxtk, 3);             \
    }
#define CACHED_KK(ck)                                               \
    {                                                               \
        const f16x8 bh = *(const f16x8*)(rp + (ck) * 1024);         \
        const f16x8 a0 = *(const f16x8*)(lds + (((w * 4 + 0) * 4 + (ck)) * 1024) + lane * 16); \
        const f16x8 a1 = *(const f16x8*)(lds + (((w * 4 + 1) * 4 + (ck)) * 1024) + lane * 16); \
        const f16x8 a2 = *(const f16x8*)(lds + (((w * 4 + 2) * 4 + (ck)) * 1024) + lane * 16); \
        const f16x8 a3 = *(const f16x8*)(lds + (((w * 4 + 3) * 4 + (ck)) * 1024) + lane * 16); \
        acc0 = MFMA16(a0, bh, acc0);                                \
        acc1 = MFMA16(a1, bh, acc1);                                \
        acc2 = MFMA16(a2, bh, acc2);                                \
        acc3 = MFMA16(a3, bh, acc3);                                \
    }

    int cur = 0;
#pragma unroll 1
    for (int t = 0; t < T_STEPS; ++t) {
        const float xv = (float)xh[t * 1024 + b0 + b_];
        const char* rp = rb + cur;
        char* wq = HB + (cur ^ 16384);

        f32x4 acc0 = {0.f, 0.f, 0.f, 0.f};
        f32x4 acc1 = {0.f, 0.f, 0.f, 0.f};
        f32x4 acc2 = {0.f, 0.f, 0.f, 0.f};
        f32x4 acc3 = {0.f, 0.f, 0.f, 0.f};

        // cached slices first: compute runs while the streamed ring flies
        CACHED_KK(0) CACHED_KK(1) CACHED_KK(2) CACHED_KK(3)
        // streamed slices (rotated order); tail reloads prefetch next step
        STEP_KK(ks[0], r0, ks[4])   STEP_KK(ks[1], r1, ks[5])
        STEP_KK(ks[2], r2, ks[6])   STEP_KK(ks[3], r3, ks[7])
        STEP_KK(ks[4], r0, ks[8])   STEP_KK(ks[5], r1, ks[9])
        STEP_KK(ks[6], r2, ks[10])  STEP_KK(ks[7], r3, ks[11])
        STEP_KK(ks[8], r0, ks[0])   STEP_KK(ks[9], r1, ks[1])
        STEP_KK(ks[10], r2, ks[2])  STEP_KK(ks[11], r3, ks[3])

        // epilogue: inject + relu, 4 x 8B stores into the OTHER h buffer
        {
            f16x4 hv;
            float v;
#define EPI(n, ACC)                                                  \
            v = ACC[0] + xv * (float)win[n][0]; hv[0] = (f16)fmaxf(v, 0.f); \
            v = ACC[1] + xv * (float)win[n][1]; hv[1] = (f16)fmaxf(v, 0.f); \
            v = ACC[2] + xv * (float)win[n][2]; hv[2] = (f16)fmaxf(v, 0.f); \
            v = ACC[3] + xv * (float)win[n][3]; hv[3] = (f16)fmaxf(v, 0.f); \
            *(f16x4*)(wq + wa[n]) = hv;
            EPI(0, acc0) EPI(1, acc1) EPI(2, acc2) EPI(3, acc3)
#undef EPI
        }

        BAR_LGKM();   // single barrier: h(t+1) visible; ring stays in flight
        cur ^= 16384;
    }

    // projection: out[b,c] = h_last[b,:] . W_out[c,:] + b_out[c]
    if (tid < 16 * COUT) {
        const int bb = tid / COUT, c = tid % COUT;
        const char* hr = HB + cur;
        float s_ = b_out[c];
        const float* wo = W_out + c * HDIM;
#pragma unroll 4
        for (int o0 = 0; o0 < HDIM; o0 += 8) {
            const int off = (o0 >> 5) * 1024 + (((((o0 >> 3) & 3) << 4) | bb) * 16);
            f16x8 hv = *(const f16x8*)(hr + off);
#pragma unroll
            for (int jj = 0; jj < 8; ++jj)
                s_ += (float)hv[jj] * wo[o0 + jj];
        }
        out[(b0 + bb) * COUT + c] = s_;
    }
}

extern "C" void kernel_launch(void* const* d_in, const int* in_sizes, int n_in,
                              void* d_out, int out_size, void* d_ws, size_t ws_size,
                              hipStream_t stream)
{
    (void)in_sizes; (void)n_in; (void)out_size; (void)ws_size;
    const float* x     = (const float*)d_in[0];
    const float* W_in  = (const float*)d_in[1];
    const float* W_rec = (const float*)d_in[2];
    const float* W_out = (const float*)d_in[3];
    const float* b_out = (const float*)d_in[4];
    const int*   perm  = (const int*)d_in[5];
    float* out = (float*)d_out;

    f16* Wf  = (f16*)d_ws;                           // 512 KB
    f16* xhp = (f16*)((char*)d_ws + XH_OFF);         // 1.6 MB

    cvt_w<<<dim3(128), dim3(256), 0, stream>>>(W_rec, Wf);
    permute_x<<<dim3(T_STEPS * 1024 / 256), dim3(256), 0, stream>>>(x, perm, xhp);
    rnn_l2<<<dim3(64), dim3(512), 0, stream>>>(W_in, Wf, xhp, W_out, b_out, out);
}